// Round 1
// baseline (17179.893 us; speedup 1.0000x reference)
//
#include <hip/hip_runtime.h>
#include <cstddef>

#define B_TOTAL  65536
#define OBS_LEN  20
#define PRED_LEN 30
#define E_DIM    32
#define H_DIM    64

__device__ __forceinline__ float sigm(float x) {
    return __builtin_amdgcn_rcpf(1.0f + __expf(-x));
}
__device__ __forceinline__ float tanh_f(float x) {
    // tanh(x) = 2*sigmoid(2x) - 1
    return fmaf(2.0f, sigm(2.0f * x), -1.0f);
}

// One full LSTM cell step, everything in registers, fully unrolled so all
// array indices are compile-time (runtime-indexed reg arrays -> scratch).
__device__ __forceinline__ void lstm_step(
    const float e[E_DIM], float h[H_DIM], float c[H_DIM],
    const float* __restrict__ Wih, const float* __restrict__ Whh,
    const float* __restrict__ bias)
{
    float hn[H_DIM];
#pragma unroll
    for (int j = 0; j < H_DIM; ++j) {
        // PyTorch gate order: rows [0:64)=i, [64:128)=f, [128:192)=g, [192:256)=o
        float ai = bias[j];
        float af = bias[H_DIM + j];
        float ag = bias[2 * H_DIM + j];
        float ao = bias[3 * H_DIM + j];
#pragma unroll
        for (int k = 0; k < E_DIM; ++k) {
            const float xv = e[k];
            ai = fmaf(Wih[(j)             * E_DIM + k], xv, ai);
            af = fmaf(Wih[(H_DIM + j)     * E_DIM + k], xv, af);
            ag = fmaf(Wih[(2 * H_DIM + j) * E_DIM + k], xv, ag);
            ao = fmaf(Wih[(3 * H_DIM + j) * E_DIM + k], xv, ao);
        }
#pragma unroll
        for (int k = 0; k < H_DIM; ++k) {
            const float hv = h[k];
            ai = fmaf(Whh[(j)             * H_DIM + k], hv, ai);
            af = fmaf(Whh[(H_DIM + j)     * H_DIM + k], hv, af);
            ag = fmaf(Whh[(2 * H_DIM + j) * H_DIM + k], hv, ag);
            ao = fmaf(Whh[(3 * H_DIM + j) * H_DIM + k], hv, ao);
        }
        const float iv = sigm(ai);
        const float fv = sigm(af);
        const float gv = tanh_f(ag);
        const float ov = sigm(ao);
        const float cn = fmaf(fv, c[j], iv * gv);
        c[j]  = cn;
        hn[j] = ov * tanh_f(cn);
    }
#pragma unroll
    for (int j = 0; j < H_DIM; ++j) h[j] = hn[j];
}

extern "C" __global__ void __launch_bounds__(256)
traj_fused(const float* __restrict__ obs,
           const float* __restrict__ noise,
           const float* __restrict__ scene,
           const float* __restrict__ W_emb,  const float* __restrict__ b_emb,
           const float* __restrict__ Wih_e,  const float* __restrict__ Whh_e, const float* __restrict__ b_e,
           const float* __restrict__ W_h,    const float* __restrict__ b_h,
           const float* __restrict__ W_c,    const float* __restrict__ b_c,
           const float* __restrict__ Wih_d,  const float* __restrict__ Whh_d, const float* __restrict__ b_d,
           const float* __restrict__ W_out,  const float* __restrict__ b_out,
           float* __restrict__ out)
{
    const int b = blockIdx.x * blockDim.x + threadIdx.x;
    if (b >= B_TOTAL) return;

    const float* ob = obs + (size_t)b * (OBS_LEN * 2);

    float h[H_DIM], c[H_DIM];
#pragma unroll
    for (int j = 0; j < H_DIM; ++j) { h[j] = 0.0f; c[j] = 0.0f; }

    // ---------------- encoder ----------------
#pragma unroll 1
    for (int t = 0; t < OBS_LEN; ++t) {
        const float x0 = ob[t * 2 + 0];
        const float x1 = ob[t * 2 + 1];
        float e[E_DIM];
#pragma unroll
        for (int k = 0; k < E_DIM; ++k)
            e[k] = fmaxf(0.0f, fmaf(W_emb[k * 2 + 0], x0,
                                fmaf(W_emb[k * 2 + 1], x1, b_emb[k])));
        lstm_step(e, h, c, Wih_e, Whh_e, b_e);
    }

    // ---------------- cond -> decoder initial state ----------------
    // cond = [h_last(64), noise(16), scene(64)], h0 = W_h @ cond + b_h, same for c0
    float h0[H_DIM], c0[H_DIM];
#pragma unroll
    for (int j = 0; j < H_DIM; ++j) { h0[j] = b_h[j]; c0[j] = b_c[j]; }

#pragma unroll
    for (int k = 0; k < H_DIM; ++k) {          // h_last part (register-resident -> unrolled)
        const float hv = h[k];
#pragma unroll
        for (int j = 0; j < H_DIM; ++j) {
            h0[j] = fmaf(W_h[j * 144 + k], hv, h0[j]);
            c0[j] = fmaf(W_c[j * 144 + k], hv, c0[j]);
        }
    }
#pragma unroll 1
    for (int k = 0; k < 16; ++k) {             // noise part (runtime k ok: global load)
        const float nv = noise[(size_t)b * 16 + k];
#pragma unroll
        for (int j = 0; j < H_DIM; ++j) {
            h0[j] = fmaf(W_h[j * 144 + 64 + k], nv, h0[j]);
            c0[j] = fmaf(W_c[j * 144 + 64 + k], nv, c0[j]);
        }
    }
#pragma unroll 1
    for (int k = 0; k < 64; ++k) {             // scene part
        const float sv = scene[(size_t)b * 64 + k];
#pragma unroll
        for (int j = 0; j < H_DIM; ++j) {
            h0[j] = fmaf(W_h[j * 144 + 80 + k], sv, h0[j]);
            c0[j] = fmaf(W_c[j * 144 + 80 + k], sv, c0[j]);
        }
    }
#pragma unroll
    for (int j = 0; j < H_DIM; ++j) { h[j] = h0[j]; c[j] = c0[j]; }

    // ---------------- autoregressive decoder ----------------
    float x0 = ob[(OBS_LEN - 1) * 2 + 0];
    float x1 = ob[(OBS_LEN - 1) * 2 + 1];
    float* op = out + (size_t)b * (PRED_LEN * 2);

#pragma unroll 1
    for (int t = 0; t < PRED_LEN; ++t) {
        float e[E_DIM];
#pragma unroll
        for (int k = 0; k < E_DIM; ++k)
            e[k] = fmaxf(0.0f, fmaf(W_emb[k * 2 + 0], x0,
                                fmaf(W_emb[k * 2 + 1], x1, b_emb[k])));
        lstm_step(e, h, c, Wih_d, Whh_d, b_d);

        float y0 = b_out[0];
        float y1 = b_out[1];
#pragma unroll
        for (int j = 0; j < H_DIM; ++j) {
            y0 = fmaf(W_out[j],         h[j], y0);
            y1 = fmaf(W_out[H_DIM + j], h[j], y1);
        }
        op[t * 2 + 0] = y0;
        op[t * 2 + 1] = y1;
        x0 = y0;
        x1 = y1;
    }
}

extern "C" void kernel_launch(void* const* d_in, const int* in_sizes, int n_in,
                              void* d_out, int out_size, void* d_ws, size_t ws_size,
                              hipStream_t stream) {
    (void)in_sizes; (void)n_in; (void)d_ws; (void)ws_size; (void)out_size;
    const float* obs    = (const float*)d_in[0];
    const float* noise  = (const float*)d_in[1];
    const float* scene  = (const float*)d_in[2];
    const float* W_emb  = (const float*)d_in[3];
    const float* b_emb  = (const float*)d_in[4];
    const float* Wih_e  = (const float*)d_in[5];
    const float* Whh_e  = (const float*)d_in[6];
    const float* b_e    = (const float*)d_in[7];
    const float* W_h    = (const float*)d_in[8];
    const float* b_h    = (const float*)d_in[9];
    const float* W_c    = (const float*)d_in[10];
    const float* b_c    = (const float*)d_in[11];
    const float* Wih_d  = (const float*)d_in[12];
    const float* Whh_d  = (const float*)d_in[13];
    const float* b_d    = (const float*)d_in[14];
    const float* W_out  = (const float*)d_in[15];
    const float* b_out  = (const float*)d_in[16];
    float* out = (float*)d_out;

    dim3 grid(B_TOTAL / 256), block(256);
    hipLaunchKernelGGL(traj_fused, grid, block, 0, stream,
                       obs, noise, scene, W_emb, b_emb,
                       Wih_e, Whh_e, b_e, W_h, b_h, W_c, b_c,
                       Wih_d, Whh_d, b_d, W_out, b_out, out);
}